// Round 6
// baseline (113.420 us; speedup 1.0000x reference)
//
#include <hip/hip_runtime.h>

#define BATCH  65536
#define NIN    9
#define NHID   100
#define TSTEPS 25
#define GSZ    8              // lanes cooperating on one batch element

// f64 m-chain (hidden spike decisions bit-identical to rounds 2/4/5) with
// f32 fc2 accumulators (acc[25] float2 = 50 VGPRs). Round-6 change: GSZ 4->8.
// Per-batch work is GSZ-invariant, so this doubles wave count (8192 waves,
// 8/SIMD of work) for latency hiding at fixed ~110-reg state, and makes the
// residency tail fine-grained. Neuron split 13/13/13/13/12/12/12/12.
__global__ __launch_bounds__(256, 4) void snn_kernel(
    const float* __restrict__ x,  const float* __restrict__ W1,
    const float* __restrict__ b1, const float* __restrict__ W2,
    const float* __restrict__ b2, float* __restrict__ out)
{
    __shared__ double sW1[NHID * NIN];   // [h][i], promoted to f64
    __shared__ double sb1[NHID];
    __shared__ float  sW2[2 * NHID];     // [o][h], f32 (feeds f32 acc FMAs)
    __shared__ double sb2[2];

    int tid = threadIdx.x;
    for (int i = tid; i < NHID * NIN; i += 256) sW1[i] = (double)W1[i];
    if (tid < NHID)     sb1[tid] = (double)b1[tid];
    if (tid < 2 * NHID) sW2[tid] = W2[tid];
    if (tid < 2)        sb2[tid] = (double)b2[tid];
    __syncthreads();

    int gtid = blockIdx.x * 256 + tid;
    int b  = gtid >> 3;     // batch element
    int hp = gtid & 7;      // neuron-slice owned by this lane

    int cnt = (hp < 4) ? 13 : 12;                       // neurons this lane
    int h0  = (hp < 4) ? hp * 13 : 52 + (hp - 4) * 12;  // first neuron

    // x row in f32 (exact); widened at use inside the f64 dot.
    float xv[NIN];
    const float* xp = x + b * NIN;
#pragma unroll
    for (int i = 0; i < NIN; ++i) xv[i] = xp[i];

    // per-step fc2 partial sums: f32 pair (50 VGPRs)
    float2 acc[TSTEPS];
#pragma unroll
    for (int t = 0; t < TSTEPS; ++t) acc[t] = make_float2(0.f, 0.f);

#pragma unroll 1
    for (int j = 0; j < cnt; ++j) {
        int h = h0 + j;
        const double* wr = &sW1[h * NIN];
        double c = 0.0;
#pragma unroll
        for (int i = 0; i < NIN; ++i) c += wr[i] * (double)xv[i];
        c += sb1[h];                       // same per-neuron order -> same spikes
        double c1 = c - 1.0;               // addend when previous step spiked
        float w0 = sW2[h], w1 = sW2[NHID + h];

        double m = 0.0;
        bool s = false;                    // spike(t-1) == reset(t)
#pragma unroll
        for (int t = 0; t < TSTEPS; ++t) {
            m = 0.95 * m + (s ? c1 : c);   // f64 leaky integrate + fused reset
            s = (m > 1.0);                 // f64 spike decision (unchanged)
            float d = s ? 1.f : 0.f;
            acc[t].x = fmaf(d, w0, acc[t].x);
            acc[t].y = fmaf(d, w1, acc[t].y);
        }
    }

    // reduce the 8 partial fc2 sums per octet (width-8 butterfly, f32)
#pragma unroll
    for (int t = 0; t < TSTEPS; ++t) {
        float v0 = acc[t].x, v1 = acc[t].y;
        v0 += __shfl_xor(v0, 1);  v0 += __shfl_xor(v0, 2);  v0 += __shfl_xor(v0, 4);
        v1 += __shfl_xor(v1, 1);  v1 += __shfl_xor(v1, 2);  v1 += __shfl_xor(v1, 4);
        acc[t].x = v0;  acc[t].y = v1;
    }

    // mem2 recurrence in f64; lane hp==0 stores f32
    if (hp == 0) {
        double m20 = 0.0, m21 = 0.0;
        double bb0 = sb2[0], bb1 = sb2[1];
        float* op = out + (size_t)b * 2;
#pragma unroll
        for (int t = 0; t < TSTEPS; ++t) {
            double r0 = (m20 > 1.0) ? 1.0 : 0.0;
            double r1 = (m21 > 1.0) ? 1.0 : 0.0;
            m20 = 0.95 * m20 + ((double)acc[t].x + bb0) - r0;
            m21 = 0.95 * m21 + ((double)acc[t].y + bb1) - r1;
            *(float2*)(op + (size_t)t * (BATCH * 2)) =
                make_float2((float)m20, (float)m21);
        }
    }
}

extern "C" void kernel_launch(void* const* d_in, const int* in_sizes, int n_in,
                              void* d_out, int out_size, void* d_ws, size_t ws_size,
                              hipStream_t stream) {
    const float* x  = (const float*)d_in[0];
    const float* W1 = (const float*)d_in[1];
    const float* b1 = (const float*)d_in[2];
    const float* W2 = (const float*)d_in[3];
    const float* b2 = (const float*)d_in[4];
    float* out = (float*)d_out;

    dim3 grid((BATCH * GSZ) / 256), block(256);
    hipLaunchKernelGGL(snn_kernel, grid, block, 0, stream, x, W1, b1, W2, b2, out);
}

// Round 7
// 101.460 us; speedup vs baseline: 1.1179x; 1.1179x over previous
//
#include <hip/hip_runtime.h>

#define BATCH  65536
#define NIN    9
#define NHID   100
#define TSTEPS 25
#define GSZ    4              // lanes cooperating on one batch element (8 had LDS conflicts)
#define HPT    (NHID / GSZ)   // 25 hidden neurons per lane

typedef float v2f __attribute__((ext_vector_type(2)));

// f64 m-chain (spike decisions track the f64 numpy arbiter) + f32 packed
// fc2 accumulators. Round-7: two independent neuron chains interleaved per
// iteration so the serial fma_f64->cmp->cndmask chain (~24 cyc latency) is
// covered by the sibling chain's issue (~32 cyc spacing) — latency-tolerant
// even at the reg-bound 2-3 waves/SIMD residency. acc as v_pk_fma_f32.
// fc2 add order == round 5 (ascending j) -> bit-identical output.
__global__ __launch_bounds__(256, 4) void snn_kernel(
    const float* __restrict__ x,  const float* __restrict__ W1,
    const float* __restrict__ b1, const float* __restrict__ W2,
    const float* __restrict__ b2, float* __restrict__ out)
{
    __shared__ double sW1[NHID * NIN];   // [h][i], promoted to f64
    __shared__ double sb1[NHID];
    __shared__ float  sW2[2 * NHID];     // [o][h], f32 (feeds packed f32 acc)
    __shared__ double sb2[2];

    int tid = threadIdx.x;
    for (int i = tid; i < NHID * NIN; i += 256) sW1[i] = (double)W1[i];
    if (tid < NHID)     sb1[tid] = (double)b1[tid];
    if (tid < 2 * NHID) sW2[tid] = W2[tid];
    if (tid < 2)        sb2[tid] = (double)b2[tid];
    __syncthreads();

    int gtid = blockIdx.x * 256 + tid;
    int b  = gtid >> 2;     // batch element
    int hp = gtid & 3;      // neuron-quarter owned by this lane

    // x row widened once to f64 (18 regs) — no per-neuron cvts in the dot.
    double xv[NIN];
    const float* xp = x + b * NIN;
#pragma unroll
    for (int i = 0; i < NIN; ++i) xv[i] = (double)xp[i];

    // per-step fc2 partial sums: packed f32 pair (50 VGPRs)
    v2f acc[TSTEPS];
#pragma unroll
    for (int t = 0; t < TSTEPS; ++t) acc[t] = (v2f){0.f, 0.f};

    int h0 = hp * HPT;

    // 12 pairs of neurons, chains interleaved for ILP
#pragma unroll 1
    for (int j = 0; j < HPT - 1; j += 2) {
        int hA = h0 + j, hB = hA + 1;
        const double* wrA = &sW1[hA * NIN];
        const double* wrB = &sW1[hB * NIN];
        double cA = 0.0, cB = 0.0;
#pragma unroll
        for (int i = 0; i < NIN; ++i) {
            double xd = xv[i];
            cA += wrA[i] * xd;
            cB += wrB[i] * xd;
        }
        cA += sb1[hA];            cB += sb1[hB];
        double cA1 = cA - 1.0,    cB1 = cB - 1.0;
        v2f wA = (v2f){sW2[hA], sW2[NHID + hA]};
        v2f wB = (v2f){sW2[hB], sW2[NHID + hB]};

        double mA = 0.0, mB = 0.0;
        bool sA = false, sB = false;   // spike(t-1) == reset(t)
#pragma unroll
        for (int t = 0; t < TSTEPS; ++t) {
            mA = 0.95 * mA + (sA ? cA1 : cA);
            mB = 0.95 * mB + (sB ? cB1 : cB);
            sA = (mA > 1.0);
            sB = (mB > 1.0);
            float dA = sA ? 1.f : 0.f;
            float dB = sB ? 1.f : 0.f;
            v2f dAv = {dA, dA};
            v2f dBv = {dB, dB};
            acc[t] += dAv * wA;        // A (=2j) then B (=2j+1): ascending j,
            acc[t] += dBv * wB;        // same fc2 order as round 5
        }
    }

    // tail neuron (j = 24)
    {
        int h = h0 + HPT - 1;
        const double* wr = &sW1[h * NIN];
        double c = 0.0;
#pragma unroll
        for (int i = 0; i < NIN; ++i) c += wr[i] * xv[i];
        c += sb1[h];
        double c1 = c - 1.0;
        v2f w = (v2f){sW2[h], sW2[NHID + h]};
        double m = 0.0;
        bool s = false;
#pragma unroll
        for (int t = 0; t < TSTEPS; ++t) {
            m = 0.95 * m + (s ? c1 : c);
            s = (m > 1.0);
            float d = s ? 1.f : 0.f;
            v2f dv = {d, d};
            acc[t] += dv * w;
        }
    }

    // reduce the 4 partial fc2 sums per quad (width-4 butterfly, f32)
#pragma unroll
    for (int t = 0; t < TSTEPS; ++t) {
        float v0 = acc[t][0], v1 = acc[t][1];
        v0 += __shfl_xor(v0, 1);  v0 += __shfl_xor(v0, 2);
        v1 += __shfl_xor(v1, 1);  v1 += __shfl_xor(v1, 2);
        acc[t][0] = v0;  acc[t][1] = v1;
    }

    // mem2 recurrence in f64; lane hp==0 stores f32
    if (hp == 0) {
        double m20 = 0.0, m21 = 0.0;
        double bb0 = sb2[0], bb1 = sb2[1];
        float* op = out + (size_t)b * 2;
#pragma unroll
        for (int t = 0; t < TSTEPS; ++t) {
            double r0 = (m20 > 1.0) ? 1.0 : 0.0;
            double r1 = (m21 > 1.0) ? 1.0 : 0.0;
            m20 = 0.95 * m20 + ((double)acc[t][0] + bb0) - r0;
            m21 = 0.95 * m21 + ((double)acc[t][1] + bb1) - r1;
            *(float2*)(op + (size_t)t * (BATCH * 2)) =
                make_float2((float)m20, (float)m21);
        }
    }
}

extern "C" void kernel_launch(void* const* d_in, const int* in_sizes, int n_in,
                              void* d_out, int out_size, void* d_ws, size_t ws_size,
                              hipStream_t stream) {
    const float* x  = (const float*)d_in[0];
    const float* W1 = (const float*)d_in[1];
    const float* b1 = (const float*)d_in[2];
    const float* W2 = (const float*)d_in[3];
    const float* b2 = (const float*)d_in[4];
    float* out = (float*)d_out;

    dim3 grid((BATCH * GSZ) / 256), block(256);
    hipLaunchKernelGGL(snn_kernel, grid, block, 0, stream, x, W1, b1, W2, b2, out);
}